// Round 10
// baseline (245.968 us; speedup 1.0000x reference)
//
#include <hip/hip_runtime.h>

// ---------------------------------------------------------------------------
// GaussianDiffusionTrainer forward, coefficient-precompute pipeline:
//   K_coef: coef[img] = {P[t_img-1], C[t_img-1]}   (all scattered gathers, once)
//   K_main: out = x0 * Pt + diag(nrm) * Ct         (pure stream, 12 f4/thread)
// (8192, 3, 32, 32) fp32.  P,C = compile-time constexpr tables.
//
// R9 -> R10: Little's-law fix. All prior rounds (2.05-2.3 TB/s) starved
// concurrency: 1-3 KB in flight per wave + 1-2Kcy scalar/barrier startup
// chains. Now: 12 float4 loads per thread issued into named registers
// BEFORE any use (12 KB/wave in flight), coefficients via dense s_loads
// from L2-warm ws (scattered table gathers hoisted into K_coef), no
// barrier, diag dwords predicated (L3-resident, R2 evidence).
// ---------------------------------------------------------------------------

constexpr int T_STEPS = 1000;
constexpr int BATCH   = 8192;
constexpr int IMGS_PER_BLOCK = 4;
constexpr int MAIN_BLOCKS = BATCH / IMGS_PER_BLOCK;   // 2048
constexpr int COEF_BLOCKS = BATCH / 256;              // 32

struct Tables { float P[T_STEPS]; float C[T_STEPS]; };

constexpr double csqrt_d(double x) {
    if (x <= 0.0) return 0.0;
    double scale = 1.0;
    while (x < 0.25) { x *= 4.0;  scale *= 0.5; }
    while (x >= 1.0) { x *= 0.25; scale *= 2.0; }
    double g = 0.5 * (x + 1.0);
    for (int i = 0; i < 40; ++i) {
        double ng = 0.5 * (g + x / g);
        if (ng == g) break;
        g = ng;
    }
    return g * scale;   // scale is a power of two -> exact
}

constexpr Tables make_tables() {
    Tables t{};
    const float beta1 = 1e-4f;
    const float betaT = 0.02f;
    const float delta = (betaT - beta1) / 1000.0f;
    float ac = 1.0f, P = 1.0f, c = 0.0f;
    for (int k = 0; k < T_STEPS; ++k) {
        float beta = beta1 + (float)k * delta;
        ac = ac * (1.0f - beta);
        float s = (float)csqrt_d((double)ac);
        P = P * s;
        c = c * s + beta * beta;
        t.P[k] = P;
        t.C[k] = c;
    }
    return t;
}

__device__ __constant__ Tables d_tbl = make_tables();

// K_coef: one thread per image; all scattered gathers live here, once.
__global__ __launch_bounds__(256) void coef_kernel(
    const int* __restrict__ tsteps,
    float2*    __restrict__ coef)
{
    const int i = blockIdx.x * 256 + threadIdx.x;   // 0..8191
    const int t = tsteps[i] - 1;                    // in [0, 999]
    coef[i] = make_float2(d_tbl.P[t], d_tbl.C[t]);
}

// K_main: block = 4 images = 3072 f4. Thread tid owns f4 (block_base + j*256
// + tid), j = 0..11; within-channel f4 index == tid for every j, so diagonal
// geometry is loop-invariant. Coefficients: 4 dense wave-uniform s_loads.
__global__ __launch_bounds__(256) void main_kernel(
    const float*  __restrict__ x0,
    const float*  __restrict__ nrm,
    const float2* __restrict__ coef,
    float*        __restrict__ out)
{
    const int b   = blockIdx.x;
    const int tid = threadIdx.x;

    // Dense, wave-uniform coefficient loads (L2-warm from K_coef).
    const float2* cp = coef + b * IMGS_PER_BLOCK;
    const float2 c0 = cp[0];
    const float2 c1 = cp[1];
    const float2 c2 = cp[2];
    const float2 c3 = cp[3];

    // Loop-invariant diagonal geometry.
    const int h  = tid >> 3;
    const int w0 = (tid & 7) << 2;
    const int d  = h - w0;
    const bool has_diag = (unsigned)d < 4u;

    const int f0 = b * 3072 + tid;                   // first f4 index
    const float4* __restrict__ x4 = reinterpret_cast<const float4*>(x0);
    float4*       __restrict__ o4 = reinterpret_cast<float4*>(out);

    // Issue all 12 independent f4 loads before ANY use.
    float4 x[12];
    #pragma unroll
    for (int j = 0; j < 12; ++j) x[j] = x4[f0 + j * 256];

    // Predicated diagonal dwords (8 active lanes/wave; lines L3-resident).
    float nv[12];
    #pragma unroll
    for (int j = 0; j < 12; ++j) nv[j] = 0.0f;
    if (has_diag) {
        #pragma unroll
        for (int j = 0; j < 12; ++j) nv[j] = nrm[((f0 + j * 256) << 2) + d];
    }

    #pragma unroll
    for (int j = 0; j < 12; ++j) {
        const int img = j / 3;                       // compile-time per unroll
        const float Pt = (img == 0) ? c0.x : (img == 1) ? c1.x : (img == 2) ? c2.x : c3.x;
        const float Ct = (img == 0) ? c0.y : (img == 1) ? c1.y : (img == 2) ? c2.y : c3.y;
        float4 r;
        r.x = x[j].x * Pt + (d == 0 ? nv[j] * Ct : 0.0f);
        r.y = x[j].y * Pt + (d == 1 ? nv[j] * Ct : 0.0f);
        r.z = x[j].z * Pt + (d == 2 ? nv[j] * Ct : 0.0f);
        r.w = x[j].w * Pt + (d == 3 ? nv[j] * Ct : 0.0f);
        o4[f0 + j * 256] = r;
    }
}

extern "C" void kernel_launch(void* const* d_in, const int* in_sizes, int n_in,
                              void* d_out, int out_size, void* d_ws, size_t ws_size,
                              hipStream_t stream) {
    const float* x0     = (const float*)d_in[0];
    const float* nrm    = (const float*)d_in[1];
    const int*   tsteps = (const int*)d_in[2];
    float*       out    = (float*)d_out;
    float2*      coef   = (float2*)d_ws;             // 8192 * 8 B = 64 KB

    coef_kernel<<<COEF_BLOCKS, 256, 0, stream>>>(tsteps, coef);
    main_kernel<<<MAIN_BLOCKS, 256, 0, stream>>>(x0, nrm, coef, out);
}